// Round 9
// baseline (323.331 us; speedup 1.0000x reference)
//
#include <hip/hip_runtime.h>
#include <hip/hip_fp16.h>

#define BN_EPS 1e-5f
#define BK 512        // dst-nodes per bucket (contiguous node range)
#define NBMAX 128
#define ECH 8192      // edges per scatter block
#define BCAP 9216     // fixed per-bucket capacity (mean 8163, sigma~90 -> 11+ sigma)
#define ECAP 64       // staged edge-index capacity per node (Poisson(16): P(>64)~1e-20)

typedef _Float16 half_t;
typedef _Float16 half8 __attribute__((ext_vector_type(8)));
typedef float floatx4 __attribute__((ext_vector_type(4)));

// ---------------------------------------------------------------------------
// Preprocess, fixed-stride buckets: bucket b owns tmp/esrc[b*BCAP ..).
// tmp entries are PACKED: (src<<9)|(dst&511)  (src<2^17, BK=512) -> 4B not 8B.
// ---------------------------------------------------------------------------

// blocks [0, sb): scatter packed {src,dstlocal} into bucket-major tmp.
// blocks [sb, ..): fp32 -> fp16 copy of x (independent work, merged dispatch).
__global__ __launch_bounds__(256) void scatter_cvt_kernel(
    const int* __restrict__ src, const int* __restrict__ dst,
    int* __restrict__ bcursor, unsigned* __restrict__ tmp,
    const float* __restrict__ x, __half* __restrict__ x16,
    int E, int nb, int sb, int n4) {
  const int t = threadIdx.x;
  if (blockIdx.x >= sb) {
    int i = (blockIdx.x - sb) * 256 + t;
    if (i < n4) {
      float4 v = *(const float4*)(x + (size_t)i * 4);
      union { __half h[4]; float2 f; } u;
      u.h[0] = __float2half_rn(v.x);
      u.h[1] = __float2half_rn(v.y);
      u.h[2] = __float2half_rn(v.z);
      u.h[3] = __float2half_rn(v.w);
      *(float2*)(x16 + (size_t)i * 4) = u.f;
    }
    return;
  }
  __shared__ int h[NBMAX];
  for (int i = t; i < nb; i += 256) h[i] = 0;
  __syncthreads();
  const int base = blockIdx.x * ECH;
#pragma unroll 8
  for (int p = 0; p < ECH / 256; ++p) {
    int e = base + p * 256 + t;
    if (e < E) atomicAdd(&h[dst[e] >> 9], 1);
  }
  __syncthreads();
  for (int i = t; i < nb; i += 256) {
    int c = h[i];
    h[i] = c ? (i * BCAP + atomicAdd(&bcursor[i], c)) : 0;  // contiguous run
  }
  __syncthreads();
#pragma unroll 8
  for (int p = 0; p < ECH / 256; ++p) {
    int e = base + p * 256 + t;
    if (e < E) {
      int s = src[e], d = dst[e];
      int pos = atomicAdd(&h[d >> 9], 1);
      tmp[pos] = ((unsigned)s << 9) | (unsigned)(d & 511);
    }
  }
}

// One block per bucket: LDS degree count -> local scan -> offs/offe/dinv/esrc.
// Also pre-scales this bucket's x16 rows by dinv[row] (dinv-fold for layer 0).
__global__ __launch_bounds__(256) void bucket_finalize_kernel(
    const unsigned* __restrict__ tmp, const int* __restrict__ bcursor,
    int* __restrict__ offs, int* __restrict__ offe, float* __restrict__ dinv,
    int* __restrict__ esrc, __half* __restrict__ x16, int n) {
  __shared__ int deg[BK];
  __shared__ int cur[BK];
  __shared__ float fdi[BK];
  __shared__ int ts[256];
  const int t = threadIdx.x;
  const int b = blockIdx.x;
  const int nbase = b * BK;
  const int nn = min(BK, n - nbase);
  const int cnt = bcursor[b];
  const unsigned* tp = tmp + (size_t)b * BCAP;
  for (int i = t; i < nn; i += 256) deg[i] = 0;
  __syncthreads();
  for (int e = t; e < cnt; e += 256)
    atomicAdd(&deg[tp[e] & 511u], 1);
  __syncthreads();
  // exclusive scan of 512 degrees (thread t handles 2t, 2t+1)
  int d0 = (2 * t < nn) ? deg[2 * t] : 0;
  int d1 = (2 * t + 1 < nn) ? deg[2 * t + 1] : 0;
  ts[t] = d0 + d1;
  __syncthreads();
  for (int o = 1; o < 256; o <<= 1) {
    int v = (t >= o) ? ts[t - o] : 0;
    __syncthreads();
    ts[t] += v;
    __syncthreads();
  }
  int base = b * BCAP + ((t == 0) ? 0 : ts[t - 1]);
  if (2 * t < nn) {
    float di = rsqrtf(1.0f + (float)d0);
    offs[nbase + 2 * t] = base;
    offe[nbase + 2 * t] = base + d0;
    cur[2 * t] = base;
    fdi[2 * t] = di;
    dinv[nbase + 2 * t] = di;
  }
  if (2 * t + 1 < nn) {
    float di = rsqrtf(1.0f + (float)d1);
    offs[nbase + 2 * t + 1] = base + d0;
    offe[nbase + 2 * t + 1] = base + d0 + d1;
    cur[2 * t + 1] = base + d0;
    fdi[2 * t + 1] = di;
    dinv[nbase + 2 * t + 1] = di;
  }
  __syncthreads();
  for (int e = t; e < cnt; e += 256) {
    unsigned r = tp[e];
    int pos = atomicAdd(&cur[r & 511u], 1);
    esrc[pos] = (int)(r >> 9);
  }
  // pre-scale x16 rows of this bucket by dinv[row] (32 half2 per row)
  __half2* xp = (__half2*)x16;
  for (int i = t; i < nn * 32; i += 256) {
    int nl = i >> 5;
    size_t idx = (((size_t)(nbase + nl)) << 5) + (i & 31);
    float2 v = __half22float2(xp[idx]);
    float s = fdi[nl];
    xp[idx] = __floats2half2_rn(v.x * s, v.y * s);
  }
}

// ---------------------------------------------------------------------------
// MFMA fp16 GEMM (fp32 accumulate).  256 thr = 4 waves; 128-row tile.
// EPI: 0 none, 1 bias+relu, 2 bias, 3 bias+BN+relu,
//      4 row-scale (bias ptr = per-row dinv; writes dinv[row]*acc).
// ---------------------------------------------------------------------------

template <int FIN, int FOUT, int EPI, bool HALFOUT>
__global__ __launch_bounds__(256) void mgemm_kernel(
    const __half* __restrict__ X, const float* __restrict__ W,
    const float* __restrict__ bias, const float* __restrict__ gam,
    const float* __restrict__ bet, const float* __restrict__ mean,
    const float* __restrict__ var, void* __restrict__ Yv, int n) {
  constexpr int LDK = 72;
  constexpr int NCI = FOUT / 16;
  __shared__ half_t Asm[128 * LDK];
  __shared__ half_t Bsm[FOUT * LDK];

  const int t = threadIdx.x;
  const int wave = t >> 6, lane = t & 63;
  const int quad = lane >> 4, l16 = lane & 15;
  const int rowBase = blockIdx.x * 128;

  floatx4 acc[2][NCI];
#pragma unroll
  for (int i = 0; i < 2; ++i)
#pragma unroll
    for (int ci = 0; ci < NCI; ++ci) acc[i][ci] = (floatx4){0.f, 0.f, 0.f, 0.f};

  for (int kc = 0; kc < FIN; kc += 64) {
    __syncthreads();
    {
      const int kq = t & 15, m0 = t >> 4;
#pragma unroll
      for (int p = 0; p < 8; ++p) {
        int m = p * 16 + m0;
        int row = rowBase + m;
        uint2 v = make_uint2(0u, 0u);
        if (row < n) v = *(const uint2*)(X + (size_t)row * FIN + kc + kq * 4);
        *(uint2*)&Asm[m * LDK + kq * 4] = v;
      }
    }
    {
#pragma unroll
      for (int c0 = 0; c0 < FOUT * 16; c0 += 256) {
        int c = c0 + t;
        int nn = c % FOUT;
        int kg = (c / FOUT) * 4;
        const float* wp = W + (size_t)(kc + kg) * FOUT + nn;
        half_t* d = &Bsm[nn * LDK + kg];
        d[0] = (half_t)wp[0];
        d[1] = (half_t)wp[FOUT];
        d[2] = (half_t)wp[2 * FOUT];
        d[3] = (half_t)wp[3 * FOUT];
      }
    }
    __syncthreads();
#pragma unroll
    for (int kk = 0; kk < 2; ++kk) {
      half8 a0 = *(const half8*)&Asm[(wave * 32 + l16) * LDK + kk * 32 + quad * 8];
      half8 a1 = *(const half8*)&Asm[(wave * 32 + 16 + l16) * LDK + kk * 32 + quad * 8];
#pragma unroll
      for (int ci = 0; ci < NCI; ++ci) {
        half8 b = *(const half8*)&Bsm[(ci * 16 + l16) * LDK + kk * 32 + quad * 8];
        acc[0][ci] = __builtin_amdgcn_mfma_f32_16x16x32_f16(a0, b, acc[0][ci], 0, 0, 0);
        acc[1][ci] = __builtin_amdgcn_mfma_f32_16x16x32_f16(a1, b, acc[1][ci], 0, 0, 0);
      }
    }
  }

  float sc[NCI], sh[NCI];
#pragma unroll
  for (int ci = 0; ci < NCI; ++ci) {
    int col = ci * 16 + l16;
    if constexpr (EPI == 3) {
      float s = gam[col] * rsqrtf(var[col] + BN_EPS);
      sc[ci] = s;
      sh[ci] = (bias[col] - mean[col]) * s + bet[col];
    } else if constexpr (EPI == 1 || EPI == 2) {
      sc[ci] = 1.f;
      sh[ci] = bias[col];
    } else {
      sc[ci] = 1.f;
      sh[ci] = 0.f;
    }
  }
  float rs[2][4];
  if constexpr (EPI == 4) {
#pragma unroll
    for (int ri = 0; ri < 2; ++ri)
#pragma unroll
      for (int r = 0; r < 4; ++r) {
        int row = rowBase + wave * 32 + ri * 16 + quad * 4 + r;
        rs[ri][r] = (row < n) ? bias[row] : 0.f;   // bias ptr = dinv (per-row)
      }
  }
#pragma unroll
  for (int ri = 0; ri < 2; ++ri)
#pragma unroll
    for (int ci = 0; ci < NCI; ++ci) {
      int col = ci * 16 + l16;
#pragma unroll
      for (int r = 0; r < 4; ++r) {
        int row = rowBase + wave * 32 + ri * 16 + quad * 4 + r;
        if (row < n) {
          float v = acc[ri][ci][r];
          if constexpr (EPI == 4) v *= rs[ri][r];
          if constexpr (EPI == 1 || EPI == 2 || EPI == 3) v = fmaf(v, sc[ci], sh[ci]);
          if constexpr (EPI == 1 || EPI == 3) v = fmaxf(v, 0.f);
          if constexpr (HALFOUT)
            ((half_t*)Yv)[(size_t)row * FOUT + col] = (half_t)v;
          else
            ((float*)Yv)[(size_t)row * FOUT + col] = v;
        }
      }
    }
}

// ---------------------------------------------------------------------------
// Fused MLP: Y = relu(X@W1+b1)@W2 + b2.  H kept in LDS (fp16, stride 136).
// ---------------------------------------------------------------------------

__global__ __launch_bounds__(256) void mlp_kernel(
    const __half* __restrict__ X, const float* __restrict__ W1,
    const float* __restrict__ b1f, const float* __restrict__ W2,
    const float* __restrict__ b2f, float* __restrict__ Y, int n) {
  constexpr int LDK = 72;
  constexpr int LDK2 = 136;
  __shared__ half_t smem[(128 + 64) * LDK2];
  half_t* As1 = smem;
  half_t* Bs1 = smem + 128 * LDK;
  half_t* As2 = smem;
  half_t* Bs2 = smem + 128 * LDK2;

  const int t = threadIdx.x;
  const int wave = t >> 6, lane = t & 63;
  const int quad = lane >> 4, l16 = lane & 15;
  const int rowBase = blockIdx.x * 128;

  floatx4 acc[2][8];
#pragma unroll
  for (int i = 0; i < 2; ++i)
#pragma unroll
    for (int ci = 0; ci < 8; ++ci) acc[i][ci] = (floatx4){0.f, 0.f, 0.f, 0.f};

  for (int kc = 0; kc < 128; kc += 64) {
    __syncthreads();
    {
      const int kq = t & 15, m0 = t >> 4;
#pragma unroll
      for (int p = 0; p < 8; ++p) {
        int m = p * 16 + m0;
        int row = rowBase + m;
        uint2 v = make_uint2(0u, 0u);
        if (row < n) v = *(const uint2*)(X + (size_t)row * 128 + kc + kq * 4);
        *(uint2*)&As1[m * LDK + kq * 4] = v;
      }
    }
    {
#pragma unroll
      for (int c0 = 0; c0 < 128 * 16; c0 += 256) {
        int c = c0 + t;
        int nn = c & 127;
        int kg = (c >> 7) << 2;
        const float* wp = W1 + (size_t)(kc + kg) * 128 + nn;
        half_t* d = &Bs1[nn * LDK + kg];
        d[0] = (half_t)wp[0];
        d[1] = (half_t)wp[128];
        d[2] = (half_t)wp[256];
        d[3] = (half_t)wp[384];
      }
    }
    __syncthreads();
#pragma unroll
    for (int kk = 0; kk < 2; ++kk) {
      half8 a0 = *(const half8*)&As1[(wave * 32 + l16) * LDK + kk * 32 + quad * 8];
      half8 a1 = *(const half8*)&As1[(wave * 32 + 16 + l16) * LDK + kk * 32 + quad * 8];
#pragma unroll
      for (int ci = 0; ci < 8; ++ci) {
        half8 b = *(const half8*)&Bs1[(ci * 16 + l16) * LDK + kk * 32 + quad * 8];
        acc[0][ci] = __builtin_amdgcn_mfma_f32_16x16x32_f16(a0, b, acc[0][ci], 0, 0, 0);
        acc[1][ci] = __builtin_amdgcn_mfma_f32_16x16x32_f16(a1, b, acc[1][ci], 0, 0, 0);
      }
    }
  }
  __syncthreads();

#pragma unroll
  for (int ri = 0; ri < 2; ++ri)
#pragma unroll
    for (int ci = 0; ci < 8; ++ci) {
      int col = ci * 16 + l16;
      float bz = b1f[col];
#pragma unroll
      for (int r = 0; r < 4; ++r) {
        int m = wave * 32 + ri * 16 + quad * 4 + r;
        As2[m * LDK2 + col] = (half_t)fmaxf(acc[ri][ci][r] + bz, 0.f);
      }
    }
  {
#pragma unroll
    for (int c0 = 0; c0 < 64 * 32; c0 += 256) {
      int c = c0 + t;
      int nn = c & 63;
      int kg = (c >> 6) << 2;
      const float* wp = W2 + (size_t)kg * 64 + nn;
      half_t* d = &Bs2[nn * LDK2 + kg];
      d[0] = (half_t)wp[0];
      d[1] = (half_t)wp[64];
      d[2] = (half_t)wp[128];
      d[3] = (half_t)wp[192];
    }
  }
  __syncthreads();

  floatx4 acc2[2][4];
#pragma unroll
  for (int i = 0; i < 2; ++i)
#pragma unroll
    for (int ci = 0; ci < 4; ++ci) acc2[i][ci] = (floatx4){0.f, 0.f, 0.f, 0.f};
#pragma unroll
  for (int kk = 0; kk < 4; ++kk) {
    half8 a0 = *(const half8*)&As2[(wave * 32 + l16) * LDK2 + kk * 32 + quad * 8];
    half8 a1 = *(const half8*)&As2[(wave * 32 + 16 + l16) * LDK2 + kk * 32 + quad * 8];
#pragma unroll
    for (int ci = 0; ci < 4; ++ci) {
      half8 b = *(const half8*)&Bs2[(ci * 16 + l16) * LDK2 + kk * 32 + quad * 8];
      acc2[0][ci] = __builtin_amdgcn_mfma_f32_16x16x32_f16(a0, b, acc2[0][ci], 0, 0, 0);
      acc2[1][ci] = __builtin_amdgcn_mfma_f32_16x16x32_f16(a1, b, acc2[1][ci], 0, 0, 0);
    }
  }
#pragma unroll
  for (int ri = 0; ri < 2; ++ri)
#pragma unroll
    for (int ci = 0; ci < 4; ++ci) {
      int col = ci * 16 + l16;
      float bz = b2f[col];
#pragma unroll
      for (int r = 0; r < 4; ++r) {
        int row = rowBase + wave * 32 + ri * 16 + quad * 4 + r;
        if (row < n) Y[(size_t)row * 64 + col] = acc2[ri][ci][r] + bz;
      }
    }
}

// ---------------------------------------------------------------------------
// Aggregations, LDS-staged edge indices, dwordx4 (16B/lane) gathers:
//   agg128: 16 lanes/row -> 4 rows per instruction; full body = 4 unmasked
//           instrs / 16 edges (32 lines in flight, half the instructions of
//           round 8); masked tail = 2 instrs / 8 edges.
//   agg64:  8 lanes/row -> 8 rows per instruction; full body = 2 instrs /
//           16 edges; masked tail = 2 instrs / 16 edges.
// Pure sums (dinv folded upstream); global fallback for deg > ECAP.
// ---------------------------------------------------------------------------

__device__ __forceinline__ void acc8(uint4 r, float* a) {
  float2 f;
  f = __half22float2(*(__half2*)&r.x); a[0] += f.x; a[1] += f.y;
  f = __half22float2(*(__half2*)&r.y); a[2] += f.x; a[3] += f.y;
  f = __half22float2(*(__half2*)&r.z); a[4] += f.x; a[5] += f.y;
  f = __half22float2(*(__half2*)&r.w); a[6] += f.x; a[7] += f.y;
}

__global__ __launch_bounds__(256) void agg64_kernel(
    const __half* __restrict__ h, const int* __restrict__ offs,
    const int* __restrict__ offe, const int* __restrict__ esrc,
    const float* __restrict__ dinv, __half* __restrict__ out, int n) {
  __shared__ int eidx[4][ECAP];
  const int wid = threadIdx.x >> 6;
  int gi = blockIdx.x * 4 + wid;
  if (gi >= n) return;
  const int lane = threadIdx.x & 63;
  const int slot = lane >> 3;         // row slot 0..7 (8 rows per instr)
  const int part = lane & 7;          // 16B chunk: feats 8*part..8*part+7
  const uint4* hp = (const uint4*)h;  // 8 uint4 per 64-feat row
  const float di = dinv[gi];
  const int e0 = offs[gi];
  const int e1 = offe[gi];
  const int deg = e1 - e0;
  const int dm = min(deg, ECAP);
  if (lane < dm) eidx[wid][lane] = esrc[e0 + lane];   // wave-local stage

  float a[8] = {0.f, 0.f, 0.f, 0.f, 0.f, 0.f, 0.f, 0.f};
  float b[8] = {0.f, 0.f, 0.f, 0.f, 0.f, 0.f, 0.f, 0.f};
  int k = 0;
  // full body: 16 edges, 2 unmasked 8-row loads
  for (; k + 16 <= dm; k += 16) {
    int s0 = eidx[wid][k + slot];
    int s1 = eidx[wid][k + 8 + slot];
    uint4 r0 = hp[(((size_t)s0) << 3) + part];
    uint4 r1 = hp[(((size_t)s1) << 3) + part];
    acc8(r0, a);
    acc8(r1, b);
  }
  // masked tail: 16 edges, 2 loads, clamp+zero
  const int mm = dm - 1;
  const uint4 z = make_uint4(0u, 0u, 0u, 0u);
  for (; k < dm; k += 16) {
    int i0 = k + slot, i1 = k + 8 + slot;
    int s0 = eidx[wid][min(i0, mm)];
    int s1 = eidx[wid][min(i1, mm)];
    uint4 r0 = hp[(((size_t)s0) << 3) + part];
    uint4 r1 = hp[(((size_t)s1) << 3) + part];
    if (i0 >= dm) r0 = z;
    if (i1 >= dm) r1 = z;
    acc8(r0, a);
    acc8(r1, b);
  }
  // fallback: deg > ECAP (practically never; kept for correctness)
  for (int e = e0 + ECAP; e < e1; e += 8) {
    int i0 = e + slot;
    int s0 = esrc[min(i0, e1 - 1)];
    uint4 r0 = hp[(((size_t)s0) << 3) + part];
    if (i0 >= e1) r0 = z;
    acc8(r0, a);
  }
#pragma unroll
  for (int i = 0; i < 8; ++i) a[i] += b[i];
  // combine the 8 row slots (lanes part, part+8, ..., part+56 hold same feats)
#pragma unroll
  for (int i = 0; i < 8; ++i) {
    a[i] += __shfl_xor(a[i], 8);
    a[i] += __shfl_xor(a[i], 16);
    a[i] += __shfl_xor(a[i], 32);
  }
  if (slot == 0) {
    uint4 rs = hp[(((size_t)gi) << 3) + part];   // self (pre-scaled row)
    float s[8] = {0.f, 0.f, 0.f, 0.f, 0.f, 0.f, 0.f, 0.f};
    acc8(rs, s);
    __half2 h0 = __floats2half2_rn(di * (a[0] + s[0]), di * (a[1] + s[1]));
    __half2 h1 = __floats2half2_rn(di * (a[2] + s[2]), di * (a[3] + s[3]));
    __half2 h2 = __floats2half2_rn(di * (a[4] + s[4]), di * (a[5] + s[5]));
    __half2 h3 = __floats2half2_rn(di * (a[6] + s[6]), di * (a[7] + s[7]));
    uint4 ov;
    ov.x = *(unsigned*)&h0;
    ov.y = *(unsigned*)&h1;
    ov.z = *(unsigned*)&h2;
    ov.w = *(unsigned*)&h3;
    ((uint4*)out)[(((size_t)gi) << 3) + part] = ov;
  }
}

__global__ __launch_bounds__(256) void agg128_bn_kernel(
    const __half* __restrict__ h, const int* __restrict__ offs,
    const int* __restrict__ offe, const int* __restrict__ esrc,
    const float* __restrict__ dinv,
    const float* __restrict__ bias, const float* __restrict__ gam,
    const float* __restrict__ bet, const float* __restrict__ mean,
    const float* __restrict__ var, __half* __restrict__ out, int n) {
  __shared__ int eidx[4][ECAP];
  const int wid = threadIdx.x >> 6;
  int gi = blockIdx.x * 4 + wid;
  if (gi >= n) return;
  const int lane = threadIdx.x & 63;
  const int slot = lane >> 4;         // row slot 0..3 (4 rows per instr)
  const int part = lane & 15;         // 16B chunk: feats 8*part..8*part+7
  const uint4* hp = (const uint4*)h;  // 16 uint4 per 128-feat row
  const float di = dinv[gi];
  const int e0 = offs[gi];
  const int e1 = offe[gi];
  const int deg = e1 - e0;
  const int dm = min(deg, ECAP);
  if (lane < dm) eidx[wid][lane] = esrc[e0 + lane];   // wave-local stage

  float a[8] = {0.f, 0.f, 0.f, 0.f, 0.f, 0.f, 0.f, 0.f};
  float b[8] = {0.f, 0.f, 0.f, 0.f, 0.f, 0.f, 0.f, 0.f};
  int k = 0;
  // full body: 16 edges, 4 unmasked 4-row loads (32 lines in flight)
  for (; k + 16 <= dm; k += 16) {
    int s0 = eidx[wid][k + slot];
    int s1 = eidx[wid][k + 4 + slot];
    int s2 = eidx[wid][k + 8 + slot];
    int s3 = eidx[wid][k + 12 + slot];
    uint4 r0 = hp[(((size_t)s0) << 4) + part];
    uint4 r1 = hp[(((size_t)s1) << 4) + part];
    uint4 r2 = hp[(((size_t)s2) << 4) + part];
    uint4 r3 = hp[(((size_t)s3) << 4) + part];
    acc8(r0, a);
    acc8(r1, b);
    acc8(r2, a);
    acc8(r3, b);
  }
  // masked tail: 8 edges, 2 loads, clamp+zero
  const int mm = dm - 1;
  const uint4 z = make_uint4(0u, 0u, 0u, 0u);
  for (; k < dm; k += 8) {
    int i0 = k + slot, i1 = k + 4 + slot;
    int s0 = eidx[wid][min(i0, mm)];
    int s1 = eidx[wid][min(i1, mm)];
    uint4 r0 = hp[(((size_t)s0) << 4) + part];
    uint4 r1 = hp[(((size_t)s1) << 4) + part];
    if (i0 >= dm) r0 = z;
    if (i1 >= dm) r1 = z;
    acc8(r0, a);
    acc8(r1, b);
  }
  // fallback: deg > ECAP (practically never; kept for correctness)
  for (int e = e0 + ECAP; e < e1; e += 4) {
    int i0 = e + slot;
    int s0 = esrc[min(i0, e1 - 1)];
    uint4 r0 = hp[(((size_t)s0) << 4) + part];
    if (i0 >= e1) r0 = z;
    acc8(r0, a);
  }
#pragma unroll
  for (int i = 0; i < 8; ++i) a[i] += b[i];
  // combine the 4 row slots (lanes part, part+16, part+32, part+48 same feats)
#pragma unroll
  for (int i = 0; i < 8; ++i) {
    a[i] += __shfl_xor(a[i], 16);
    a[i] += __shfl_xor(a[i], 32);
  }
  if (slot == 0) {
    uint4 rs = hp[(((size_t)gi) << 4) + part];   // self (pre-scaled row)
    float s[8] = {0.f, 0.f, 0.f, 0.f, 0.f, 0.f, 0.f, 0.f};
    acc8(rs, s);
    const int c = part * 8;
    float o[8];
#pragma unroll
    for (int i = 0; i < 8; i += 4) {
      float4 bv = *(const float4*)(bias + c + i);
      float4 gv = *(const float4*)(gam + c + i);
      float4 bev = *(const float4*)(bet + c + i);
      float4 mv = *(const float4*)(mean + c + i);
      float4 vv = *(const float4*)(var + c + i);
      float v0 = di * (a[i + 0] + s[i + 0]);
      float v1 = di * (a[i + 1] + s[i + 1]);
      float v2 = di * (a[i + 2] + s[i + 2]);
      float v3 = di * (a[i + 3] + s[i + 3]);
      o[i + 0] = fmaxf(fmaf(v0 + bv.x - mv.x, gv.x * rsqrtf(vv.x + BN_EPS), bev.x), 0.f);
      o[i + 1] = fmaxf(fmaf(v1 + bv.y - mv.y, gv.y * rsqrtf(vv.y + BN_EPS), bev.y), 0.f);
      o[i + 2] = fmaxf(fmaf(v2 + bv.z - mv.z, gv.z * rsqrtf(vv.z + BN_EPS), bev.z), 0.f);
      o[i + 3] = fmaxf(fmaf(v3 + bv.w - mv.w, gv.w * rsqrtf(vv.w + BN_EPS), bev.w), 0.f);
    }
    __half2 h0 = __floats2half2_rn(o[0], o[1]);
    __half2 h1 = __floats2half2_rn(o[2], o[3]);
    __half2 h2 = __floats2half2_rn(o[4], o[5]);
    __half2 h3 = __floats2half2_rn(o[6], o[7]);
    uint4 ov;
    ov.x = *(unsigned*)&h0;
    ov.y = *(unsigned*)&h1;
    ov.z = *(unsigned*)&h2;
    ov.w = *(unsigned*)&h3;
    ((uint4*)out)[(((size_t)gi) << 4) + part] = ov;
  }
}

// ---------------------------------------------------------------------------

static inline size_t alignup(size_t x, size_t a) { return (x + a - 1) & ~(a - 1); }

extern "C" void kernel_launch(void* const* d_in, const int* in_sizes, int n_in,
                              void* d_out, int out_size, void* d_ws, size_t ws_size,
                              hipStream_t stream) {
  const float* x   = (const float*)d_in[0];
  const int*   src = (const int*)d_in[1];
  const int*   dst = (const int*)d_in[2];
  const float* W0  = (const float*)d_in[3];
  const float* b0  = (const float*)d_in[4];
  const float* g0  = (const float*)d_in[5];
  const float* be0 = (const float*)d_in[6];
  const float* m0  = (const float*)d_in[7];
  const float* v0  = (const float*)d_in[8];
  const float* W1  = (const float*)d_in[9];
  const float* b1  = (const float*)d_in[10];
  const float* g1  = (const float*)d_in[11];
  const float* be1 = (const float*)d_in[12];
  const float* m1  = (const float*)d_in[13];
  const float* v1  = (const float*)d_in[14];
  const float* W2  = (const float*)d_in[15];
  const float* b2  = (const float*)d_in[16];
  const float* g2  = (const float*)d_in[17];
  const float* be2 = (const float*)d_in[18];
  const float* m2  = (const float*)d_in[19];
  const float* v2  = (const float*)d_in[20];
  const float* Wm1 = (const float*)d_in[21];
  const float* bm1 = (const float*)d_in[22];
  const float* Wm2 = (const float*)d_in[23];
  const float* bm2 = (const float*)d_in[24];

  const int N = in_sizes[0] / 64;
  const int E = in_sizes[1];

  char* p = (char*)d_ws;
  auto take = [&](size_t bytes) {
    char* r = p;
    p += alignup(bytes, 256);
    return r;
  };
  const int nbk = (N + BK - 1) / BK;    // buckets (98 for N=50000)
  int*      bcursor= (int*)take(NBMAX * 4);
  int*      offs   = (int*)take((size_t)N * 4);
  int*      offe   = (int*)take((size_t)N * 4);
  float*    dinv   = (float*)take((size_t)N * 4);
  int*      esrc   = (int*)take((size_t)nbk * BCAP * 4);
  unsigned* tmp    = (unsigned*)take((size_t)nbk * BCAP * 4);
  __half*   x16    = (__half*)take((size_t)N * 64 * 2);
  __half*   aggx16 = (__half*)take((size_t)N * 64 * 2);
  __half*   t0     = (__half*)take((size_t)N * 128 * 2);
  __half*   t1     = (__half*)take((size_t)N * 128 * 2);
  float*    yout   = (float*)d_out;

  const int TB = 256;
  const int sb = (E + ECH - 1) / ECH;   // scatter blocks
  const int n4 = N * 16;                // float4 count of x
  const int cb = (n4 + 255) / 256;      // cvt blocks

  // --- CSR build (fixed-stride buckets) + fp16 x, 3 dispatches total ---
  hipMemsetAsync(bcursor, 0, NBMAX * 4, stream);
  scatter_cvt_kernel<<<sb + cb, TB, 0, stream>>>(src, dst, bcursor, tmp,
                                                 x, x16, E, nbk, sb, n4);
  bucket_finalize_kernel<<<nbk, TB, 0, stream>>>(tmp, bcursor, offs, offe,
                                                 dinv, esrc, x16, N);

  const int gemmGrid = (N + 127) / 128;
  const int aggGrid = (N + 3) / 4;

  // --- layer 0 (x16 rows pre-scaled by dinv in finalize; agg is pure sum) ---
  agg64_kernel<<<aggGrid, TB, 0, stream>>>(x16, offs, offe, esrc, dinv, aggx16, N);
  mgemm_kernel<64, 128, 3, true><<<gemmGrid, TB, 0, stream>>>(
      aggx16, W0, b0, g0, be0, m0, v0, t0, N);
  // --- layer 1 (GEMM pre-scales rows by dinv via EPI=4; agg sums + BN) ---
  mgemm_kernel<128, 128, 4, true><<<gemmGrid, TB, 0, stream>>>(
      t0, W1, dinv, nullptr, nullptr, nullptr, nullptr, t1, N);
  agg128_bn_kernel<<<aggGrid, TB, 0, stream>>>(t1, offs, offe, esrc, dinv,
                                               b1, g1, be1, m1, v1, t0, N);
  // --- layer 2 ---
  mgemm_kernel<128, 128, 4, true><<<gemmGrid, TB, 0, stream>>>(
      t0, W2, dinv, nullptr, nullptr, nullptr, nullptr, t1, N);
  agg128_bn_kernel<<<aggGrid, TB, 0, stream>>>(t1, offs, offe, esrc, dinv,
                                               b2, g2, be2, m2, v2, t0, N);
  // --- fused MLP ---
  mlp_kernel<<<gemmGrid, TB, 0, stream>>>(t0, Wm1, bm1, Wm2, bm2, yout, N);
}

// Round 10
// 313.509 us; speedup vs baseline: 1.0313x; 1.0313x over previous
//
#include <hip/hip_runtime.h>
#include <hip/hip_fp16.h>

#define BN_EPS 1e-5f
#define BK 512        // dst-nodes per bucket (contiguous node range)
#define NBMAX 128
#define ECH 8192      // edges per scatter block
#define BCAP 9216     // fixed per-bucket capacity (mean 8163, sigma~90 -> 11+ sigma)
#define ECAP 64       // staged edge-index capacity per node (Poisson(16): P(>64)~1e-20)

typedef _Float16 half_t;
typedef _Float16 half8 __attribute__((ext_vector_type(8)));
typedef float floatx4 __attribute__((ext_vector_type(4)));

// ---------------------------------------------------------------------------
// Preprocess, fixed-stride buckets: bucket b owns tmp/esrc[b*BCAP ..).
// tmp entries are PACKED: (src<<9)|(dst&511)  (src<2^17, BK=512) -> 4B not 8B.
// ---------------------------------------------------------------------------

// blocks [0, sb): scatter packed {src,dstlocal} into bucket-major tmp.
// blocks [sb, ..): fp32 -> fp16 copy of x (independent work, merged dispatch).
__global__ __launch_bounds__(256) void scatter_cvt_kernel(
    const int* __restrict__ src, const int* __restrict__ dst,
    int* __restrict__ bcursor, unsigned* __restrict__ tmp,
    const float* __restrict__ x, __half* __restrict__ x16,
    int E, int nb, int sb, int n4) {
  const int t = threadIdx.x;
  if (blockIdx.x >= sb) {
    int i = (blockIdx.x - sb) * 256 + t;
    if (i < n4) {
      float4 v = *(const float4*)(x + (size_t)i * 4);
      union { __half h[4]; float2 f; } u;
      u.h[0] = __float2half_rn(v.x);
      u.h[1] = __float2half_rn(v.y);
      u.h[2] = __float2half_rn(v.z);
      u.h[3] = __float2half_rn(v.w);
      *(float2*)(x16 + (size_t)i * 4) = u.f;
    }
    return;
  }
  __shared__ int h[NBMAX];
  for (int i = t; i < nb; i += 256) h[i] = 0;
  __syncthreads();
  const int base = blockIdx.x * ECH;
#pragma unroll 8
  for (int p = 0; p < ECH / 256; ++p) {
    int e = base + p * 256 + t;
    if (e < E) atomicAdd(&h[dst[e] >> 9], 1);
  }
  __syncthreads();
  for (int i = t; i < nb; i += 256) {
    int c = h[i];
    h[i] = c ? (i * BCAP + atomicAdd(&bcursor[i], c)) : 0;  // contiguous run
  }
  __syncthreads();
#pragma unroll 8
  for (int p = 0; p < ECH / 256; ++p) {
    int e = base + p * 256 + t;
    if (e < E) {
      int s = src[e], d = dst[e];
      int pos = atomicAdd(&h[d >> 9], 1);
      tmp[pos] = ((unsigned)s << 9) | (unsigned)(d & 511);
    }
  }
}

// One block per bucket: LDS degree count -> local scan -> offs/offe/dinv/esrc.
// Also pre-scales this bucket's x16 rows by dinv[row] (dinv-fold for layer 0).
__global__ __launch_bounds__(256) void bucket_finalize_kernel(
    const unsigned* __restrict__ tmp, const int* __restrict__ bcursor,
    int* __restrict__ offs, int* __restrict__ offe, float* __restrict__ dinv,
    int* __restrict__ esrc, __half* __restrict__ x16, int n) {
  __shared__ int deg[BK];
  __shared__ int cur[BK];
  __shared__ float fdi[BK];
  __shared__ int ts[256];
  const int t = threadIdx.x;
  const int b = blockIdx.x;
  const int nbase = b * BK;
  const int nn = min(BK, n - nbase);
  const int cnt = bcursor[b];
  const unsigned* tp = tmp + (size_t)b * BCAP;
  for (int i = t; i < nn; i += 256) deg[i] = 0;
  __syncthreads();
  for (int e = t; e < cnt; e += 256)
    atomicAdd(&deg[tp[e] & 511u], 1);
  __syncthreads();
  // exclusive scan of 512 degrees (thread t handles 2t, 2t+1)
  int d0 = (2 * t < nn) ? deg[2 * t] : 0;
  int d1 = (2 * t + 1 < nn) ? deg[2 * t + 1] : 0;
  ts[t] = d0 + d1;
  __syncthreads();
  for (int o = 1; o < 256; o <<= 1) {
    int v = (t >= o) ? ts[t - o] : 0;
    __syncthreads();
    ts[t] += v;
    __syncthreads();
  }
  int base = b * BCAP + ((t == 0) ? 0 : ts[t - 1]);
  if (2 * t < nn) {
    float di = rsqrtf(1.0f + (float)d0);
    offs[nbase + 2 * t] = base;
    offe[nbase + 2 * t] = base + d0;
    cur[2 * t] = base;
    fdi[2 * t] = di;
    dinv[nbase + 2 * t] = di;
  }
  if (2 * t + 1 < nn) {
    float di = rsqrtf(1.0f + (float)d1);
    offs[nbase + 2 * t + 1] = base + d0;
    offe[nbase + 2 * t + 1] = base + d0 + d1;
    cur[2 * t + 1] = base + d0;
    fdi[2 * t + 1] = di;
    dinv[nbase + 2 * t + 1] = di;
  }
  __syncthreads();
  for (int e = t; e < cnt; e += 256) {
    unsigned r = tp[e];
    int pos = atomicAdd(&cur[r & 511u], 1);
    esrc[pos] = (int)(r >> 9);
  }
  // pre-scale x16 rows of this bucket by dinv[row] (32 half2 per row)
  __half2* xp = (__half2*)x16;
  for (int i = t; i < nn * 32; i += 256) {
    int nl = i >> 5;
    size_t idx = (((size_t)(nbase + nl)) << 5) + (i & 31);
    float2 v = __half22float2(xp[idx]);
    float s = fdi[nl];
    xp[idx] = __floats2half2_rn(v.x * s, v.y * s);
  }
}

// ---------------------------------------------------------------------------
// MFMA fp16 GEMM (fp32 accumulate).  256 thr = 4 waves; 128-row tile.
// EPI: 0 none, 1 bias+relu, 2 bias, 3 bias+BN+relu,
//      4 row-scale (bias ptr = per-row dinv; writes dinv[row]*acc).
// ---------------------------------------------------------------------------

template <int FIN, int FOUT, int EPI, bool HALFOUT>
__global__ __launch_bounds__(256) void mgemm_kernel(
    const __half* __restrict__ X, const float* __restrict__ W,
    const float* __restrict__ bias, const float* __restrict__ gam,
    const float* __restrict__ bet, const float* __restrict__ mean,
    const float* __restrict__ var, void* __restrict__ Yv, int n) {
  constexpr int LDK = 72;
  constexpr int NCI = FOUT / 16;
  __shared__ half_t Asm[128 * LDK];
  __shared__ half_t Bsm[FOUT * LDK];

  const int t = threadIdx.x;
  const int wave = t >> 6, lane = t & 63;
  const int quad = lane >> 4, l16 = lane & 15;
  const int rowBase = blockIdx.x * 128;

  floatx4 acc[2][NCI];
#pragma unroll
  for (int i = 0; i < 2; ++i)
#pragma unroll
    for (int ci = 0; ci < NCI; ++ci) acc[i][ci] = (floatx4){0.f, 0.f, 0.f, 0.f};

  for (int kc = 0; kc < FIN; kc += 64) {
    __syncthreads();
    {
      const int kq = t & 15, m0 = t >> 4;
#pragma unroll
      for (int p = 0; p < 8; ++p) {
        int m = p * 16 + m0;
        int row = rowBase + m;
        uint2 v = make_uint2(0u, 0u);
        if (row < n) v = *(const uint2*)(X + (size_t)row * FIN + kc + kq * 4);
        *(uint2*)&Asm[m * LDK + kq * 4] = v;
      }
    }
    {
#pragma unroll
      for (int c0 = 0; c0 < FOUT * 16; c0 += 256) {
        int c = c0 + t;
        int nn = c % FOUT;
        int kg = (c / FOUT) * 4;
        const float* wp = W + (size_t)(kc + kg) * FOUT + nn;
        half_t* d = &Bsm[nn * LDK + kg];
        d[0] = (half_t)wp[0];
        d[1] = (half_t)wp[FOUT];
        d[2] = (half_t)wp[2 * FOUT];
        d[3] = (half_t)wp[3 * FOUT];
      }
    }
    __syncthreads();
#pragma unroll
    for (int kk = 0; kk < 2; ++kk) {
      half8 a0 = *(const half8*)&Asm[(wave * 32 + l16) * LDK + kk * 32 + quad * 8];
      half8 a1 = *(const half8*)&Asm[(wave * 32 + 16 + l16) * LDK + kk * 32 + quad * 8];
#pragma unroll
      for (int ci = 0; ci < NCI; ++ci) {
        half8 b = *(const half8*)&Bsm[(ci * 16 + l16) * LDK + kk * 32 + quad * 8];
        acc[0][ci] = __builtin_amdgcn_mfma_f32_16x16x32_f16(a0, b, acc[0][ci], 0, 0, 0);
        acc[1][ci] = __builtin_amdgcn_mfma_f32_16x16x32_f16(a1, b, acc[1][ci], 0, 0, 0);
      }
    }
  }

  float sc[NCI], sh[NCI];
#pragma unroll
  for (int ci = 0; ci < NCI; ++ci) {
    int col = ci * 16 + l16;
    if constexpr (EPI == 3) {
      float s = gam[col] * rsqrtf(var[col] + BN_EPS);
      sc[ci] = s;
      sh[ci] = (bias[col] - mean[col]) * s + bet[col];
    } else if constexpr (EPI == 1 || EPI == 2) {
      sc[ci] = 1.f;
      sh[ci] = bias[col];
    } else {
      sc[ci] = 1.f;
      sh[ci] = 0.f;
    }
  }
  float rs[2][4];
  if constexpr (EPI == 4) {
#pragma unroll
    for (int ri = 0; ri < 2; ++ri)
#pragma unroll
      for (int r = 0; r < 4; ++r) {
        int row = rowBase + wave * 32 + ri * 16 + quad * 4 + r;
        rs[ri][r] = (row < n) ? bias[row] : 0.f;   // bias ptr = dinv (per-row)
      }
  }
#pragma unroll
  for (int ri = 0; ri < 2; ++ri)
#pragma unroll
    for (int ci = 0; ci < NCI; ++ci) {
      int col = ci * 16 + l16;
#pragma unroll
      for (int r = 0; r < 4; ++r) {
        int row = rowBase + wave * 32 + ri * 16 + quad * 4 + r;
        if (row < n) {
          float v = acc[ri][ci][r];
          if constexpr (EPI == 4) v *= rs[ri][r];
          if constexpr (EPI == 1 || EPI == 2 || EPI == 3) v = fmaf(v, sc[ci], sh[ci]);
          if constexpr (EPI == 1 || EPI == 3) v = fmaxf(v, 0.f);
          if constexpr (HALFOUT)
            ((half_t*)Yv)[(size_t)row * FOUT + col] = (half_t)v;
          else
            ((float*)Yv)[(size_t)row * FOUT + col] = v;
        }
      }
    }
}

// ---------------------------------------------------------------------------
// Fused MLP: Y = relu(X@W1+b1)@W2 + b2.  H kept in LDS (fp16, stride 136).
// ---------------------------------------------------------------------------

__global__ __launch_bounds__(256) void mlp_kernel(
    const __half* __restrict__ X, const float* __restrict__ W1,
    const float* __restrict__ b1f, const float* __restrict__ W2,
    const float* __restrict__ b2f, float* __restrict__ Y, int n) {
  constexpr int LDK = 72;
  constexpr int LDK2 = 136;
  __shared__ half_t smem[(128 + 64) * LDK2];
  half_t* As1 = smem;
  half_t* Bs1 = smem + 128 * LDK;
  half_t* As2 = smem;
  half_t* Bs2 = smem + 128 * LDK2;

  const int t = threadIdx.x;
  const int wave = t >> 6, lane = t & 63;
  const int quad = lane >> 4, l16 = lane & 15;
  const int rowBase = blockIdx.x * 128;

  floatx4 acc[2][8];
#pragma unroll
  for (int i = 0; i < 2; ++i)
#pragma unroll
    for (int ci = 0; ci < 8; ++ci) acc[i][ci] = (floatx4){0.f, 0.f, 0.f, 0.f};

  for (int kc = 0; kc < 128; kc += 64) {
    __syncthreads();
    {
      const int kq = t & 15, m0 = t >> 4;
#pragma unroll
      for (int p = 0; p < 8; ++p) {
        int m = p * 16 + m0;
        int row = rowBase + m;
        uint2 v = make_uint2(0u, 0u);
        if (row < n) v = *(const uint2*)(X + (size_t)row * 128 + kc + kq * 4);
        *(uint2*)&As1[m * LDK + kq * 4] = v;
      }
    }
    {
#pragma unroll
      for (int c0 = 0; c0 < 128 * 16; c0 += 256) {
        int c = c0 + t;
        int nn = c & 127;
        int kg = (c >> 7) << 2;
        const float* wp = W1 + (size_t)(kc + kg) * 128 + nn;
        half_t* d = &Bs1[nn * LDK + kg];
        d[0] = (half_t)wp[0];
        d[1] = (half_t)wp[128];
        d[2] = (half_t)wp[256];
        d[3] = (half_t)wp[384];
      }
    }
    __syncthreads();
#pragma unroll
    for (int kk = 0; kk < 2; ++kk) {
      half8 a0 = *(const half8*)&As1[(wave * 32 + l16) * LDK + kk * 32 + quad * 8];
      half8 a1 = *(const half8*)&As1[(wave * 32 + 16 + l16) * LDK + kk * 32 + quad * 8];
#pragma unroll
      for (int ci = 0; ci < 8; ++ci) {
        half8 b = *(const half8*)&Bs1[(ci * 16 + l16) * LDK + kk * 32 + quad * 8];
        acc[0][ci] = __builtin_amdgcn_mfma_f32_16x16x32_f16(a0, b, acc[0][ci], 0, 0, 0);
        acc[1][ci] = __builtin_amdgcn_mfma_f32_16x16x32_f16(a1, b, acc[1][ci], 0, 0, 0);
      }
    }
  }
  __syncthreads();

#pragma unroll
  for (int ri = 0; ri < 2; ++ri)
#pragma unroll
    for (int ci = 0; ci < 8; ++ci) {
      int col = ci * 16 + l16;
      float bz = b1f[col];
#pragma unroll
      for (int r = 0; r < 4; ++r) {
        int m = wave * 32 + ri * 16 + quad * 4 + r;
        As2[m * LDK2 + col] = (half_t)fmaxf(acc[ri][ci][r] + bz, 0.f);
      }
    }
  {
#pragma unroll
    for (int c0 = 0; c0 < 64 * 32; c0 += 256) {
      int c = c0 + t;
      int nn = c & 63;
      int kg = (c >> 6) << 2;
      const float* wp = W2 + (size_t)kg * 64 + nn;
      half_t* d = &Bs2[nn * LDK2 + kg];
      d[0] = (half_t)wp[0];
      d[1] = (half_t)wp[64];
      d[2] = (half_t)wp[128];
      d[3] = (half_t)wp[192];
    }
  }
  __syncthreads();

  floatx4 acc2[2][4];
#pragma unroll
  for (int i = 0; i < 2; ++i)
#pragma unroll
    for (int ci = 0; ci < 4; ++ci) acc2[i][ci] = (floatx4){0.f, 0.f, 0.f, 0.f};
#pragma unroll
  for (int kk = 0; kk < 4; ++kk) {
    half8 a0 = *(const half8*)&As2[(wave * 32 + l16) * LDK2 + kk * 32 + quad * 8];
    half8 a1 = *(const half8*)&As2[(wave * 32 + 16 + l16) * LDK2 + kk * 32 + quad * 8];
#pragma unroll
    for (int ci = 0; ci < 4; ++ci) {
      half8 b = *(const half8*)&Bs2[(ci * 16 + l16) * LDK2 + kk * 32 + quad * 8];
      acc2[0][ci] = __builtin_amdgcn_mfma_f32_16x16x32_f16(a0, b, acc2[0][ci], 0, 0, 0);
      acc2[1][ci] = __builtin_amdgcn_mfma_f32_16x16x32_f16(a1, b, acc2[1][ci], 0, 0, 0);
    }
  }
#pragma unroll
  for (int ri = 0; ri < 2; ++ri)
#pragma unroll
    for (int ci = 0; ci < 4; ++ci) {
      int col = ci * 16 + l16;
      float bz = b2f[col];
#pragma unroll
      for (int r = 0; r < 4; ++r) {
        int row = rowBase + wave * 32 + ri * 16 + quad * 4 + r;
        if (row < n) Y[(size_t)row * 64 + col] = acc2[ri][ci][r] + bz;
      }
    }
}

// ---------------------------------------------------------------------------
// Aggregations, LDS-staged edge indices, two-tier gather loop:
//   full body:  8 UNMASKED packed row-loads back-to-back (32 lines in
//               flight/wave, zero clamp VALU, zero redundant requests)
//   masked tail: 4-load clamp+zero body
// Pure sums (dinv folded upstream); global fallback for deg > ECAP.
// ---------------------------------------------------------------------------

__global__ __launch_bounds__(256) void agg64_kernel(
    const __half* __restrict__ h, const int* __restrict__ offs,
    const int* __restrict__ offe, const int* __restrict__ esrc,
    const float* __restrict__ dinv, __half* __restrict__ out, int n) {
  __shared__ int eidx[4][ECAP];
  const int wid = threadIdx.x >> 6;
  int gi = blockIdx.x * 4 + wid;
  if (gi >= n) return;
  const int lane = threadIdx.x & 63;
  const int q = lane >> 4;            // edge slot 0..3
  const int j = lane & 15;            // feats 4j..4j+3
  const __half2* hp = (const __half2*)h;
  const float di = dinv[gi];
  const int e0 = offs[gi];
  const int e1 = offe[gi];
  const int deg = e1 - e0;
  const int dm = min(deg, ECAP);
  if (lane < dm) eidx[wid][lane] = esrc[e0 + lane];   // wave-local stage

  float ax = 0.f, ay = 0.f, az = 0.f, aw = 0.f;
  float bx = 0.f, by = 0.f, bz = 0.f, bw = 0.f;
  int k = 0;
  // full body: 32 edges, 8 unmasked loads
  for (; k + 32 <= dm; k += 32) {
    int s0 = eidx[wid][k + q];
    int s1 = eidx[wid][k + 4 + q];
    int s2 = eidx[wid][k + 8 + q];
    int s3 = eidx[wid][k + 12 + q];
    int s4 = eidx[wid][k + 16 + q];
    int s5 = eidx[wid][k + 20 + q];
    int s6 = eidx[wid][k + 24 + q];
    int s7 = eidx[wid][k + 28 + q];
    uint2 r0 = *(const uint2*)(hp + (((size_t)s0) << 5) + j * 2);
    uint2 r1 = *(const uint2*)(hp + (((size_t)s1) << 5) + j * 2);
    uint2 r2 = *(const uint2*)(hp + (((size_t)s2) << 5) + j * 2);
    uint2 r3 = *(const uint2*)(hp + (((size_t)s3) << 5) + j * 2);
    uint2 r4 = *(const uint2*)(hp + (((size_t)s4) << 5) + j * 2);
    uint2 r5 = *(const uint2*)(hp + (((size_t)s5) << 5) + j * 2);
    uint2 r6 = *(const uint2*)(hp + (((size_t)s6) << 5) + j * 2);
    uint2 r7 = *(const uint2*)(hp + (((size_t)s7) << 5) + j * 2);
    float2 f;
    f = __half22float2(*(__half2*)&r0.x); ax += f.x; ay += f.y;
    f = __half22float2(*(__half2*)&r0.y); az += f.x; aw += f.y;
    f = __half22float2(*(__half2*)&r1.x); bx += f.x; by += f.y;
    f = __half22float2(*(__half2*)&r1.y); bz += f.x; bw += f.y;
    f = __half22float2(*(__half2*)&r2.x); ax += f.x; ay += f.y;
    f = __half22float2(*(__half2*)&r2.y); az += f.x; aw += f.y;
    f = __half22float2(*(__half2*)&r3.x); bx += f.x; by += f.y;
    f = __half22float2(*(__half2*)&r3.y); bz += f.x; bw += f.y;
    f = __half22float2(*(__half2*)&r4.x); ax += f.x; ay += f.y;
    f = __half22float2(*(__half2*)&r4.y); az += f.x; aw += f.y;
    f = __half22float2(*(__half2*)&r5.x); bx += f.x; by += f.y;
    f = __half22float2(*(__half2*)&r5.y); bz += f.x; bw += f.y;
    f = __half22float2(*(__half2*)&r6.x); ax += f.x; ay += f.y;
    f = __half22float2(*(__half2*)&r6.y); az += f.x; aw += f.y;
    f = __half22float2(*(__half2*)&r7.x); bx += f.x; by += f.y;
    f = __half22float2(*(__half2*)&r7.y); bz += f.x; bw += f.y;
  }
  // masked tail: 16 edges, 4 loads, clamp+zero
  const int mm = dm - 1;
  for (; k < dm; k += 16) {
    int i0 = k + q, i1 = k + 4 + q, i2 = k + 8 + q, i3 = k + 12 + q;
    int s0 = eidx[wid][min(i0, mm)];
    int s1 = eidx[wid][min(i1, mm)];
    int s2 = eidx[wid][min(i2, mm)];
    int s3 = eidx[wid][min(i3, mm)];
    uint2 r0 = *(const uint2*)(hp + (((size_t)s0) << 5) + j * 2);
    uint2 r1 = *(const uint2*)(hp + (((size_t)s1) << 5) + j * 2);
    uint2 r2 = *(const uint2*)(hp + (((size_t)s2) << 5) + j * 2);
    uint2 r3 = *(const uint2*)(hp + (((size_t)s3) << 5) + j * 2);
    if (i0 >= dm) { r0.x = 0u; r0.y = 0u; }
    if (i1 >= dm) { r1.x = 0u; r1.y = 0u; }
    if (i2 >= dm) { r2.x = 0u; r2.y = 0u; }
    if (i3 >= dm) { r3.x = 0u; r3.y = 0u; }
    float2 f;
    f = __half22float2(*(__half2*)&r0.x); ax += f.x; ay += f.y;
    f = __half22float2(*(__half2*)&r0.y); az += f.x; aw += f.y;
    f = __half22float2(*(__half2*)&r1.x); bx += f.x; by += f.y;
    f = __half22float2(*(__half2*)&r1.y); bz += f.x; bw += f.y;
    f = __half22float2(*(__half2*)&r2.x); ax += f.x; ay += f.y;
    f = __half22float2(*(__half2*)&r2.y); az += f.x; aw += f.y;
    f = __half22float2(*(__half2*)&r3.x); bx += f.x; by += f.y;
    f = __half22float2(*(__half2*)&r3.y); bz += f.x; bw += f.y;
  }
  // fallback: deg > ECAP (practically never; kept for correctness)
  for (int e = e0 + ECAP; e < e1; e += 4) {
    int i0 = e + q;
    int s0 = esrc[min(i0, e1 - 1)];
    uint2 r0 = *(const uint2*)(hp + (((size_t)s0) << 5) + j * 2);
    if (i0 >= e1) { r0.x = 0u; r0.y = 0u; }
    float2 f;
    f = __half22float2(*(__half2*)&r0.x); ax += f.x; ay += f.y;
    f = __half22float2(*(__half2*)&r0.y); az += f.x; aw += f.y;
  }
  ax += bx; ay += by; az += bz; aw += bw;
  // combine the 4 edge groups (lanes j, j+16, j+32, j+48 hold same feats)
  ax += __shfl_xor(ax, 16); ay += __shfl_xor(ay, 16);
  az += __shfl_xor(az, 16); aw += __shfl_xor(aw, 16);
  ax += __shfl_xor(ax, 32); ay += __shfl_xor(ay, 32);
  az += __shfl_xor(az, 32); aw += __shfl_xor(aw, 32);
  if (q == 0) {
    uint2 rs = *(const uint2*)(hp + (((size_t)gi) << 5) + j * 2);  // self (scaled)
    float2 s0 = __half22float2(*(__half2*)&rs.x);
    float2 s1 = __half22float2(*(__half2*)&rs.y);
    __half2 h0 = __floats2half2_rn(di * (ax + s0.x), di * (ay + s0.y));
    __half2 h1 = __floats2half2_rn(di * (az + s1.x), di * (aw + s1.y));
    uint2 ov;
    ov.x = *(unsigned*)&h0;
    ov.y = *(unsigned*)&h1;
    *(uint2*)((__half2*)out + (((size_t)gi) << 5) + j * 2) = ov;
  }
}

__global__ __launch_bounds__(256) void agg128_bn_kernel(
    const __half* __restrict__ h, const int* __restrict__ offs,
    const int* __restrict__ offe, const int* __restrict__ esrc,
    const float* __restrict__ dinv,
    const float* __restrict__ bias, const float* __restrict__ gam,
    const float* __restrict__ bet, const float* __restrict__ mean,
    const float* __restrict__ var, __half* __restrict__ out, int n) {
  __shared__ int eidx[4][ECAP];
  const int wid = threadIdx.x >> 6;
  int gi = blockIdx.x * 4 + wid;
  if (gi >= n) return;
  const int lane = threadIdx.x & 63;
  const int hh = lane >> 5;           // half-wave: edge parity
  const int j = lane & 31;            // feats 4j..4j+3
  const __half2* hp = (const __half2*)h;
  const float di = dinv[gi];
  const int e0 = offs[gi];
  const int e1 = offe[gi];
  const int deg = e1 - e0;
  const int dm = min(deg, ECAP);
  if (lane < dm) eidx[wid][lane] = esrc[e0 + lane];   // wave-local stage

  float ax = 0.f, ay = 0.f, az = 0.f, aw = 0.f;
  float bx = 0.f, by = 0.f, bz = 0.f, bw = 0.f;
  int k = 0;
  // full body: 16 edges, 8 unmasked loads
  for (; k + 16 <= dm; k += 16) {
    int s0 = eidx[wid][k + hh];
    int s1 = eidx[wid][k + 2 + hh];
    int s2 = eidx[wid][k + 4 + hh];
    int s3 = eidx[wid][k + 6 + hh];
    int s4 = eidx[wid][k + 8 + hh];
    int s5 = eidx[wid][k + 10 + hh];
    int s6 = eidx[wid][k + 12 + hh];
    int s7 = eidx[wid][k + 14 + hh];
    uint2 r0 = *(const uint2*)(hp + (((size_t)s0) << 6) + j * 2);
    uint2 r1 = *(const uint2*)(hp + (((size_t)s1) << 6) + j * 2);
    uint2 r2 = *(const uint2*)(hp + (((size_t)s2) << 6) + j * 2);
    uint2 r3 = *(const uint2*)(hp + (((size_t)s3) << 6) + j * 2);
    uint2 r4 = *(const uint2*)(hp + (((size_t)s4) << 6) + j * 2);
    uint2 r5 = *(const uint2*)(hp + (((size_t)s5) << 6) + j * 2);
    uint2 r6 = *(const uint2*)(hp + (((size_t)s6) << 6) + j * 2);
    uint2 r7 = *(const uint2*)(hp + (((size_t)s7) << 6) + j * 2);
    float2 f;
    f = __half22float2(*(__half2*)&r0.x); ax += f.x; ay += f.y;
    f = __half22float2(*(__half2*)&r0.y); az += f.x; aw += f.y;
    f = __half22float2(*(__half2*)&r1.x); bx += f.x; by += f.y;
    f = __half22float2(*(__half2*)&r1.y); bz += f.x; bw += f.y;
    f = __half22float2(*(__half2*)&r2.x); ax += f.x; ay += f.y;
    f = __half22float2(*(__half2*)&r2.y); az += f.x; aw += f.y;
    f = __half22float2(*(__half2*)&r3.x); bx += f.x; by += f.y;
    f = __half22float2(*(__half2*)&r3.y); bz += f.x; bw += f.y;
    f = __half22float2(*(__half2*)&r4.x); ax += f.x; ay += f.y;
    f = __half22float2(*(__half2*)&r4.y); az += f.x; aw += f.y;
    f = __half22float2(*(__half2*)&r5.x); bx += f.x; by += f.y;
    f = __half22float2(*(__half2*)&r5.y); bz += f.x; bw += f.y;
    f = __half22float2(*(__half2*)&r6.x); ax += f.x; ay += f.y;
    f = __half22float2(*(__half2*)&r6.y); az += f.x; aw += f.y;
    f = __half22float2(*(__half2*)&r7.x); bx += f.x; by += f.y;
    f = __half22float2(*(__half2*)&r7.y); bz += f.x; bw += f.y;
  }
  // masked tail: 8 edges, 4 loads, clamp+zero
  const int mm = dm - 1;
  for (; k < dm; k += 8) {
    int i0 = k + hh, i1 = k + 2 + hh, i2 = k + 4 + hh, i3 = k + 6 + hh;
    int s0 = eidx[wid][min(i0, mm)];
    int s1 = eidx[wid][min(i1, mm)];
    int s2 = eidx[wid][min(i2, mm)];
    int s3 = eidx[wid][min(i3, mm)];
    uint2 r0 = *(const uint2*)(hp + (((size_t)s0) << 6) + j * 2);
    uint2 r1 = *(const uint2*)(hp + (((size_t)s1) << 6) + j * 2);
    uint2 r2 = *(const uint2*)(hp + (((size_t)s2) << 6) + j * 2);
    uint2 r3 = *(const uint2*)(hp + (((size_t)s3) << 6) + j * 2);
    if (i0 >= dm) { r0.x = 0u; r0.y = 0u; }
    if (i1 >= dm) { r1.x = 0u; r1.y = 0u; }
    if (i2 >= dm) { r2.x = 0u; r2.y = 0u; }
    if (i3 >= dm) { r3.x = 0u; r3.y = 0u; }
    float2 f;
    f = __half22float2(*(__half2*)&r0.x); ax += f.x; ay += f.y;
    f = __half22float2(*(__half2*)&r0.y); az += f.x; aw += f.y;
    f = __half22float2(*(__half2*)&r1.x); bx += f.x; by += f.y;
    f = __half22float2(*(__half2*)&r1.y); bz += f.x; bw += f.y;
    f = __half22float2(*(__half2*)&r2.x); ax += f.x; ay += f.y;
    f = __half22float2(*(__half2*)&r2.y); az += f.x; aw += f.y;
    f = __half22float2(*(__half2*)&r3.x); bx += f.x; by += f.y;
    f = __half22float2(*(__half2*)&r3.y); bz += f.x; bw += f.y;
  }
  // fallback: deg > ECAP (practically never; kept for correctness)
  for (int e = e0 + ECAP; e < e1; e += 2) {
    int i0 = e + hh;
    int s0 = esrc[min(i0, e1 - 1)];
    uint2 r0 = *(const uint2*)(hp + (((size_t)s0) << 6) + j * 2);
    if (i0 >= e1) { r0.x = 0u; r0.y = 0u; }
    float2 f;
    f = __half22float2(*(__half2*)&r0.x); ax += f.x; ay += f.y;
    f = __half22float2(*(__half2*)&r0.y); az += f.x; aw += f.y;
  }
  ax += bx; ay += by; az += bz; aw += bw;
  // combine half-waves (lanes j and j+32 hold same feats, different edges)
  ax += __shfl_xor(ax, 32); ay += __shfl_xor(ay, 32);
  az += __shfl_xor(az, 32); aw += __shfl_xor(aw, 32);
  if (hh == 0) {
    uint2 rs = *(const uint2*)(hp + (((size_t)gi) << 6) + j * 2);  // self (scaled)
    float2 s0 = __half22float2(*(__half2*)&rs.x);
    float2 s1 = __half22float2(*(__half2*)&rs.y);
    float v0 = di * (ax + s0.x);
    float v1 = di * (ay + s0.y);
    float v2 = di * (az + s1.x);
    float v3 = di * (aw + s1.y);
    const int c = j * 4;
    float4 bv = *(const float4*)(bias + c);
    float4 gv = *(const float4*)(gam + c);
    float4 bev = *(const float4*)(bet + c);
    float4 mv = *(const float4*)(mean + c);
    float4 vv = *(const float4*)(var + c);
    float o0 = fmaxf(fmaf(v0 + bv.x - mv.x, gv.x * rsqrtf(vv.x + BN_EPS), bev.x), 0.f);
    float o1 = fmaxf(fmaf(v1 + bv.y - mv.y, gv.y * rsqrtf(vv.y + BN_EPS), bev.y), 0.f);
    float o2 = fmaxf(fmaf(v2 + bv.z - mv.z, gv.z * rsqrtf(vv.z + BN_EPS), bev.z), 0.f);
    float o3 = fmaxf(fmaf(v3 + bv.w - mv.w, gv.w * rsqrtf(vv.w + BN_EPS), bev.w), 0.f);
    __half2 h0 = __floats2half2_rn(o0, o1);
    __half2 h1 = __floats2half2_rn(o2, o3);
    uint2 ov;
    ov.x = *(unsigned*)&h0;
    ov.y = *(unsigned*)&h1;
    *(uint2*)((__half2*)out + (((size_t)gi) << 6) + j * 2) = ov;
  }
}

// ---------------------------------------------------------------------------

static inline size_t alignup(size_t x, size_t a) { return (x + a - 1) & ~(a - 1); }

extern "C" void kernel_launch(void* const* d_in, const int* in_sizes, int n_in,
                              void* d_out, int out_size, void* d_ws, size_t ws_size,
                              hipStream_t stream) {
  const float* x   = (const float*)d_in[0];
  const int*   src = (const int*)d_in[1];
  const int*   dst = (const int*)d_in[2];
  const float* W0  = (const float*)d_in[3];
  const float* b0  = (const float*)d_in[4];
  const float* g0  = (const float*)d_in[5];
  const float* be0 = (const float*)d_in[6];
  const float* m0  = (const float*)d_in[7];
  const float* v0  = (const float*)d_in[8];
  const float* W1  = (const float*)d_in[9];
  const float* b1  = (const float*)d_in[10];
  const float* g1  = (const float*)d_in[11];
  const float* be1 = (const float*)d_in[12];
  const float* m1  = (const float*)d_in[13];
  const float* v1  = (const float*)d_in[14];
  const float* W2  = (const float*)d_in[15];
  const float* b2  = (const float*)d_in[16];
  const float* g2  = (const float*)d_in[17];
  const float* be2 = (const float*)d_in[18];
  const float* m2  = (const float*)d_in[19];
  const float* v2  = (const float*)d_in[20];
  const float* Wm1 = (const float*)d_in[21];
  const float* bm1 = (const float*)d_in[22];
  const float* Wm2 = (const float*)d_in[23];
  const float* bm2 = (const float*)d_in[24];

  const int N = in_sizes[0] / 64;
  const int E = in_sizes[1];

  char* p = (char*)d_ws;
  auto take = [&](size_t bytes) {
    char* r = p;
    p += alignup(bytes, 256);
    return r;
  };
  const int nbk = (N + BK - 1) / BK;    // buckets (98 for N=50000)
  int*      bcursor= (int*)take(NBMAX * 4);
  int*      offs   = (int*)take((size_t)N * 4);
  int*      offe   = (int*)take((size_t)N * 4);
  float*    dinv   = (float*)take((size_t)N * 4);
  int*      esrc   = (int*)take((size_t)nbk * BCAP * 4);
  unsigned* tmp    = (unsigned*)take((size_t)nbk * BCAP * 4);
  __half*   x16    = (__half*)take((size_t)N * 64 * 2);
  __half*   aggx16 = (__half*)take((size_t)N * 64 * 2);
  __half*   t0     = (__half*)take((size_t)N * 128 * 2);
  __half*   t1     = (__half*)take((size_t)N * 128 * 2);
  float*    yout   = (float*)d_out;

  const int TB = 256;
  const int sb = (E + ECH - 1) / ECH;   // scatter blocks
  const int n4 = N * 16;                // float4 count of x
  const int cb = (n4 + 255) / 256;      // cvt blocks

  // --- CSR build (fixed-stride buckets) + fp16 x, 3 dispatches total ---
  hipMemsetAsync(bcursor, 0, NBMAX * 4, stream);
  scatter_cvt_kernel<<<sb + cb, TB, 0, stream>>>(src, dst, bcursor, tmp,
                                                 x, x16, E, nbk, sb, n4);
  bucket_finalize_kernel<<<nbk, TB, 0, stream>>>(tmp, bcursor, offs, offe,
                                                 dinv, esrc, x16, N);

  const int gemmGrid = (N + 127) / 128;
  const int aggGrid = (N + 3) / 4;

  // --- layer 0 (x16 rows pre-scaled by dinv in finalize; agg is pure sum) ---
  agg64_kernel<<<aggGrid, TB, 0, stream>>>(x16, offs, offe, esrc, dinv, aggx16, N);
  mgemm_kernel<64, 128, 3, true><<<gemmGrid, TB, 0, stream>>>(
      aggx16, W0, b0, g0, be0, m0, v0, t0, N);
  // --- layer 1 (GEMM pre-scales rows by dinv via EPI=4; agg sums + BN) ---
  mgemm_kernel<128, 128, 4, true><<<gemmGrid, TB, 0, stream>>>(
      t0, W1, dinv, nullptr, nullptr, nullptr, nullptr, t1, N);
  agg128_bn_kernel<<<aggGrid, TB, 0, stream>>>(t1, offs, offe, esrc, dinv,
                                               b1, g1, be1, m1, v1, t0, N);
  // --- layer 2 ---
  mgemm_kernel<128, 128, 4, true><<<gemmGrid, TB, 0, stream>>>(
      t0, W2, dinv, nullptr, nullptr, nullptr, nullptr, t1, N);
  agg128_bn_kernel<<<aggGrid, TB, 0, stream>>>(t1, offs, offe, esrc, dinv,
                                               b2, g2, be2, m2, v2, t0, N);
  // --- fused MLP ---
  mlp_kernel<<<gemmGrid, TB, 0, stream>>>(t0, Wm1, bm1, Wm2, bm2, yout, N);
}